// Round 6
// baseline (404.104 us; speedup 1.0000x reference)
//
#include <hip/hip_runtime.h>
#include <math.h>

// ---------------------------------------------------------------------------
// 2-layer GCN:  out = GCNConv(relu(GCNConv(x, W1, b1)), W2, b2)
// Factorization: g = (x@W) * dinv[row];  agg[d] = g[d] + sum_{s in in(d)} g[s];
//                out[d] = agg[d]*dinv[d] + b   (dinv = rsqrt(indeg+1))
//
// R1: per-node scatter -> 197MB partial-line writebacks. Fixed (bucket sort).
// R2: per-node histogram atomics -> 99.8MB writebacks. Fixed (LDS sort).
// R3->R4: bf16 G rows halve gather fetch (364->162MB). R5: 8-edge dwordx4
//   gathers fix MLP (90->61us). R6: (a) aggregate = 8 nodes/wave, grp=node,
//   no shfl butterfly (was 24 DS-ops + 3-deep tail per node); (b) gemm 8x8
//   register blocking (was 3 LDS instr per 8 FMAs -> LDS-pipe bound ~60us).
// ---------------------------------------------------------------------------

#define BKT_SHIFT 9               // 512 nodes per bucket
#define BKT_NODES 512
#define NBSH      256             // >= bucket count (196)
#define CHUNK     8192            // edges per bucket_bin/coarse_hist block
#define MAXB      20480           // max edges/bucket for LDS sort (mean ~16.3k)

typedef unsigned short ushort_t;

static __device__ __forceinline__ unsigned short f2bf(float f) {
    unsigned u = __float_as_uint(f);
    unsigned r = (u + 0x7FFFu + ((u >> 16) & 1u)) >> 16;   // RNE
    return (unsigned short)r;
}
static __device__ __forceinline__ float bf_lo(unsigned u) {
    return __uint_as_float(u << 16);
}
static __device__ __forceinline__ float bf_hi(unsigned u) {
    return __uint_as_float(u & 0xFFFF0000u);
}
static __device__ __forceinline__ void acc_add(float2* a, uint4 v) {
    a[0].x += bf_lo(v.x); a[0].y += bf_hi(v.x);
    a[1].x += bf_lo(v.y); a[1].y += bf_hi(v.y);
    a[2].x += bf_lo(v.z); a[2].y += bf_hi(v.z);
    a[3].x += bf_lo(v.w); a[3].y += bf_hi(v.w);
}

__global__ __launch_bounds__(256) void zero_small(int* __restrict__ bhist,
                                                  int* __restrict__ bcur) {
    int t = threadIdx.x;
    bhist[t] = 0;
    bcur[t]  = 0;
}

__global__ __launch_bounds__(256) void coarse_hist(const int* __restrict__ dst,
                                                   int* __restrict__ bhist,
                                                   int E, int NB) {
    __shared__ int h[NBSH];
    const int t  = threadIdx.x;
    const int e0 = blockIdx.x * CHUNK;
    const int n  = min(CHUNK, E - e0);
    h[t] = 0;
    __syncthreads();
    for (int i = t; i < n; i += 256) atomicAdd(&h[dst[e0 + i] >> BKT_SHIFT], 1);
    __syncthreads();
    if (t < NB && h[t] > 0) atomicAdd(&bhist[t], h[t]);
}

__global__ __launch_bounds__(256) void scan196(const int* __restrict__ bhist,
                                               int* __restrict__ boffs, int NB, int E) {
    __shared__ int sh[256];
    int t = threadIdx.x;
    int orig = (t < NB) ? bhist[t] : 0;
    sh[t] = orig;
    __syncthreads();
    for (int d = 1; d < 256; d <<= 1) {
        int u = (t >= d) ? sh[t - d] : 0;
        __syncthreads();
        sh[t] += u;
        __syncthreads();
    }
    if (t < NB) boffs[t] = sh[t] - orig;  // exclusive
    if (t == NB) boffs[NB] = E;
    if (t == 255 && NB < 255) boffs[NB] = E;
}

// Phase A: bin edges into buckets. Packed pair: (dst&511)<<17 | src  (src<2^17).
__global__ __launch_bounds__(256) void bucket_bin(const int* __restrict__ src,
                                                  const int* __restrict__ dst,
                                                  const int* __restrict__ boffs,
                                                  int* __restrict__ bcur,
                                                  unsigned* __restrict__ pairs,
                                                  int E, int NB) {
    __shared__ unsigned stag[CHUNK];   // 32KB
    __shared__ int hist[NBSH];
    __shared__ int lofs[NBSH];
    __shared__ int lcur[NBSH];
    __shared__ int gbase[NBSH];
    const int t  = threadIdx.x;
    const int e0 = blockIdx.x * CHUNK;
    const int n  = min(CHUNK, E - e0);

    for (int i = t; i < NBSH; i += 256) hist[i] = 0;
    __syncthreads();
    for (int i = t; i < n; i += 256) atomicAdd(&hist[dst[e0 + i] >> BKT_SHIFT], 1);
    __syncthreads();
    int v = hist[t];
    lofs[t] = v;
    __syncthreads();
    for (int d = 1; d < 256; d <<= 1) {
        int u = (t >= d) ? lofs[t - d] : 0;
        __syncthreads();
        lofs[t] += u;
        __syncthreads();
    }
    if (t < NB) {
        lcur[t]  = lofs[t] - v;
        gbase[t] = (v > 0) ? boffs[t] + atomicAdd(&bcur[t], v) : 0;
    }
    __syncthreads();
    for (int i = t; i < n; i += 256) {
        int d = dst[e0 + i];
        int s = src[e0 + i];
        int b = d >> BKT_SHIFT;
        int p = atomicAdd(&lcur[b], 1);
        stag[p] = ((unsigned)(d & (BKT_NODES - 1)) << 17) | (unsigned)s;
    }
    __syncthreads();
    const int wv = t >> 6, ln = t & 63;
    for (int b = wv; b < NB; b += 4) {
        int cb = hist[b];
        if (cb == 0) continue;
        int lo = lofs[b] - cb;
        int gb = gbase[b];
        for (int i = ln; i < cb; i += 64) pairs[gb + i] = stag[lo + i];
    }
}

// Phase B: per-bucket fine counting sort in LDS; emits cnt/offs/dinv coalesced.
__global__ __launch_bounds__(1024) void csr_sort(const unsigned* __restrict__ pairs,
                                                 const int* __restrict__ boffs,
                                                 int* __restrict__ csr,
                                                 int* __restrict__ cnt,
                                                 int* __restrict__ offs,
                                                 float* __restrict__ dinv,
                                                 int N) {
    extern __shared__ unsigned stag2[];   // MAXB entries (80KB)
    __shared__ int lhist[BKT_NODES];
    __shared__ int lofs[BKT_NODES];
    __shared__ int ncur[BKT_NODES];
    const int b    = blockIdx.x;
    const int t    = threadIdx.x;
    const int n0   = b << BKT_SHIFT;
    const int base = boffs[b];
    const int ne   = boffs[b + 1] - base;

    if (t < BKT_NODES) lhist[t] = 0;
    __syncthreads();
    for (int i = t; i < ne; i += 1024) atomicAdd(&lhist[pairs[base + i] >> 17], 1);
    __syncthreads();
    if (t < BKT_NODES) lofs[t] = lhist[t];
    __syncthreads();
    for (int d = 1; d < BKT_NODES; d <<= 1) {
        int u = (t < BKT_NODES && t >= d) ? lofs[t - d] : 0;
        __syncthreads();
        if (t < BKT_NODES) lofs[t] += u;
        __syncthreads();
    }
    if (t < BKT_NODES) {
        int node = n0 + t;
        int ex   = lofs[t] - lhist[t];
        ncur[t]  = ex;
        if (node < N) {
            cnt[node]  = lhist[t];
            offs[node] = base + ex;
            dinv[node] = rsqrtf((float)(lhist[t] + 1));
        }
    }
    __syncthreads();
    if (ne <= MAXB) {
        for (int i = t; i < ne; i += 1024) {
            unsigned p = pairs[base + i];
            int pos = atomicAdd(&ncur[p >> 17], 1);
            stag2[pos] = p & 0x1FFFFu;
        }
        __syncthreads();
        for (int i = t; i < ne; i += 1024) csr[base + i] = (int)stag2[i];
    } else {  // safety fallback
        for (int i = t; i < ne; i += 1024) {
            unsigned p = pairs[base + i];
            int pos = atomicAdd(&ncur[p >> 17], 1);
            csr[base + pos] = (int)(p & 0x1FFFFu);
        }
    }
}

// G[row] = bf16( (X[row] @ W) * dinv[row] ).  192 rows/block, 192 threads.
// Thread tile 8 rows x 8 cols (ty=t>>3 rowgroup, tx=t&7 colgroup). K chunked
// by 32 into Xs (pitch 34: b64-aligned, ty-stride 16 banks -> 4-way, ~free).
// Per 4-k: 16 ds_read_b64 (X) + 8 ds_read_b128 (W) per 256 FMAs.
template <int K>
__global__ __launch_bounds__(192) void gemm_scale(const float* __restrict__ X,
                                                  const float* __restrict__ W,
                                                  const float* __restrict__ dinv,
                                                  ushort_t* __restrict__ G, int N) {
    __shared__ float Ws[K * 64];
    __shared__ float Xs[192 * 34];
    const int t  = threadIdx.x;
    const int r0 = blockIdx.x * 192;
    const int ty = t >> 3;   // 0..23
    const int tx = t & 7;    // 0..7

    for (int i = t; i < K * 16; i += 192)
        ((float4*)Ws)[i] = ((const float4*)W)[i];

    float4 acc0[8], acc1[8];
#pragma unroll
    for (int i = 0; i < 8; ++i) {
        acc0[i] = make_float4(0.f, 0.f, 0.f, 0.f);
        acc1[i] = make_float4(0.f, 0.f, 0.f, 0.f);
    }

    for (int kc = 0; kc < K; kc += 32) {
#pragma unroll
        for (int j = 0; j < 8; ++j) {
            int i   = t + j * 192;
            int row = i >> 3;
            int c4  = (i & 7) * 4;
            int gr  = r0 + row;
            float4 v = make_float4(0.f, 0.f, 0.f, 0.f);
            if (gr < N) v = *(const float4*)(X + (size_t)gr * K + kc + c4);
            float* p = &Xs[row * 34 + c4];
            *(float2*)p       = make_float2(v.x, v.y);
            *(float2*)(p + 2) = make_float2(v.z, v.w);
        }
        __syncthreads();
#pragma unroll
        for (int k4 = 0; k4 < 8; ++k4) {
            const int lk = k4 * 4;
            float2 xa[8], xb[8];
#pragma unroll
            for (int i = 0; i < 8; ++i) {
                const float* xp = &Xs[(ty * 8 + i) * 34 + lk];
                xa[i] = *(const float2*)xp;
                xb[i] = *(const float2*)(xp + 2);
            }
            float4 wa[4], wb[4];
#pragma unroll
            for (int kk = 0; kk < 4; ++kk) {
                const float* wp = &Ws[(kc + lk + kk) * 64 + tx * 8];
                wa[kk] = *(const float4*)wp;
                wb[kk] = *(const float4*)(wp + 4);
            }
#pragma unroll
            for (int i = 0; i < 8; ++i) {
                float xv;
                xv = xa[i].x;
                acc0[i].x = fmaf(xv, wa[0].x, acc0[i].x); acc0[i].y = fmaf(xv, wa[0].y, acc0[i].y);
                acc0[i].z = fmaf(xv, wa[0].z, acc0[i].z); acc0[i].w = fmaf(xv, wa[0].w, acc0[i].w);
                acc1[i].x = fmaf(xv, wb[0].x, acc1[i].x); acc1[i].y = fmaf(xv, wb[0].y, acc1[i].y);
                acc1[i].z = fmaf(xv, wb[0].z, acc1[i].z); acc1[i].w = fmaf(xv, wb[0].w, acc1[i].w);
                xv = xa[i].y;
                acc0[i].x = fmaf(xv, wa[1].x, acc0[i].x); acc0[i].y = fmaf(xv, wa[1].y, acc0[i].y);
                acc0[i].z = fmaf(xv, wa[1].z, acc0[i].z); acc0[i].w = fmaf(xv, wa[1].w, acc0[i].w);
                acc1[i].x = fmaf(xv, wb[1].x, acc1[i].x); acc1[i].y = fmaf(xv, wb[1].y, acc1[i].y);
                acc1[i].z = fmaf(xv, wb[1].z, acc1[i].z); acc1[i].w = fmaf(xv, wb[1].w, acc1[i].w);
                xv = xb[i].x;
                acc0[i].x = fmaf(xv, wa[2].x, acc0[i].x); acc0[i].y = fmaf(xv, wa[2].y, acc0[i].y);
                acc0[i].z = fmaf(xv, wa[2].z, acc0[i].z); acc0[i].w = fmaf(xv, wa[2].w, acc0[i].w);
                acc1[i].x = fmaf(xv, wb[2].x, acc1[i].x); acc1[i].y = fmaf(xv, wb[2].y, acc1[i].y);
                acc1[i].z = fmaf(xv, wb[2].z, acc1[i].z); acc1[i].w = fmaf(xv, wb[2].w, acc1[i].w);
                xv = xb[i].y;
                acc0[i].x = fmaf(xv, wa[3].x, acc0[i].x); acc0[i].y = fmaf(xv, wa[3].y, acc0[i].y);
                acc0[i].z = fmaf(xv, wa[3].z, acc0[i].z); acc0[i].w = fmaf(xv, wa[3].w, acc0[i].w);
                acc1[i].x = fmaf(xv, wb[3].x, acc1[i].x); acc1[i].y = fmaf(xv, wb[3].y, acc1[i].y);
                acc1[i].z = fmaf(xv, wb[3].z, acc1[i].z); acc1[i].w = fmaf(xv, wb[3].w, acc1[i].w);
            }
        }
        __syncthreads();
    }

#pragma unroll
    for (int i = 0; i < 8; ++i) {
        int r = r0 + ty * 8 + i;
        if (r < N) {
            float s = dinv[r];
            uint4 u;
            u.x = (unsigned)f2bf(acc0[i].x * s) | ((unsigned)f2bf(acc0[i].y * s) << 16);
            u.y = (unsigned)f2bf(acc0[i].z * s) | ((unsigned)f2bf(acc0[i].w * s) << 16);
            u.z = (unsigned)f2bf(acc1[i].x * s) | ((unsigned)f2bf(acc1[i].y * s) << 16);
            u.w = (unsigned)f2bf(acc1[i].z * s) | ((unsigned)f2bf(acc1[i].w * s) << 16);
            *(uint4*)(G + (size_t)r * 64 + tx * 8) = u;
        }
    }
}

// 8 nodes per wave: grp=lane>>3 picks the node, sub=lane&7 its 16B row chunk.
// Each group walks its own edge list (exec-masked divergence); one wave-gather
// still moves 8x128B. No cross-lane reduction, all 64 lanes write output.
__global__ __launch_bounds__(256) void aggregate(const ushort_t* __restrict__ G,
                                                 const int* __restrict__ offs,
                                                 const int* __restrict__ cnt,
                                                 const int* __restrict__ csr,
                                                 const float* __restrict__ dinv,
                                                 const float* __restrict__ bias,
                                                 float* __restrict__ out, int N,
                                                 int do_relu) {
    int wid  = (blockIdx.x * 256 + threadIdx.x) >> 6;
    int lane = threadIdx.x & 63;
    int grp  = lane >> 3;
    int sub  = lane & 7;
    int node = wid * 8 + grp;
    if (node >= N) return;
    const int beg = offs[node];
    const int num = cnt[node];
    const size_t subo = (size_t)sub * 8;

    float2 acc[4];
    {   // self-loop
        uint4 v = *(const uint4*)(G + (size_t)node * 64 + subo);
        acc[0] = make_float2(bf_lo(v.x), bf_hi(v.x));
        acc[1] = make_float2(bf_lo(v.y), bf_hi(v.y));
        acc[2] = make_float2(bf_lo(v.z), bf_hi(v.z));
        acc[3] = make_float2(bf_lo(v.w), bf_hi(v.w));
    }
    int e = 0;
    for (; e + 2 <= num; e += 2) {
        int i0 = csr[beg + e];
        int i1 = csr[beg + e + 1];
        uint4 v0 = *(const uint4*)(G + (size_t)i0 * 64 + subo);
        uint4 v1 = *(const uint4*)(G + (size_t)i1 * 64 + subo);
        acc_add(acc, v0);
        acc_add(acc, v1);
    }
    if (e < num) {
        int i0 = csr[beg + e];
        uint4 v0 = *(const uint4*)(G + (size_t)i0 * 64 + subo);
        acc_add(acc, v0);
    }

    float dv  = dinv[node];
    float4 b0 = *(const float4*)(bias + sub * 8);
    float4 b1 = *(const float4*)(bias + sub * 8 + 4);
    float4 o0 = make_float4(fmaf(acc[0].x, dv, b0.x), fmaf(acc[0].y, dv, b0.y),
                            fmaf(acc[1].x, dv, b0.z), fmaf(acc[1].y, dv, b0.w));
    float4 o1 = make_float4(fmaf(acc[2].x, dv, b1.x), fmaf(acc[2].y, dv, b1.y),
                            fmaf(acc[3].x, dv, b1.z), fmaf(acc[3].y, dv, b1.w));
    if (do_relu) {
        o0.x = fmaxf(o0.x, 0.f); o0.y = fmaxf(o0.y, 0.f);
        o0.z = fmaxf(o0.z, 0.f); o0.w = fmaxf(o0.w, 0.f);
        o1.x = fmaxf(o1.x, 0.f); o1.y = fmaxf(o1.y, 0.f);
        o1.z = fmaxf(o1.z, 0.f); o1.w = fmaxf(o1.w, 0.f);
    }
    *(float4*)(out + (size_t)node * 64 + sub * 8)     = o0;
    *(float4*)(out + (size_t)node * 64 + sub * 8 + 4) = o1;
}

extern "C" void kernel_launch(void* const* d_in, const int* in_sizes, int n_in,
                              void* d_out, int out_size, void* d_ws, size_t ws_size,
                              hipStream_t stream) {
    const float* x  = (const float*)d_in[0];
    const int*   ei = (const int*)d_in[1];
    const float* W1 = (const float*)d_in[2];
    const float* b1 = (const float*)d_in[3];
    const float* W2 = (const float*)d_in[4];
    const float* b2 = (const float*)d_in[5];
    float* out = (float*)d_out;

    const int IN_CH = 128;
    const int N = in_sizes[0] / IN_CH;   // 100000
    const int E = in_sizes[1] / 2;       // 3200000
    const int* src = ei;
    const int* dst = ei + E;
    const int NB = (N + BKT_NODES - 1) >> BKT_SHIFT;  // 196

    char* ws = (char*)d_ws;
    size_t off = 0;
    auto take = [&](size_t bytes) -> char* {
        char* p = ws + off;
        off += (bytes + 255) & ~(size_t)255;
        return p;
    };
    int*      cnt   = (int*)take((size_t)N * 4);
    int*      offs  = (int*)take((size_t)N * 4);
    float*    dinv  = (float*)take((size_t)N * 4);
    int*      bhist = (int*)take(NBSH * 4);
    int*      boffs = (int*)take((NBSH + 1) * 4);
    int*      bcur  = (int*)take(NBSH * 4);
    int*      csr   = (int*)take((size_t)E * 4);
    ushort_t* g     = (ushort_t*)take((size_t)E * 4);       // >= N*64*2; aliases pairs
    float*    a1    = (float*)take((size_t)N * 64 * 4);
    unsigned* pairs = (unsigned*)g;  // pairs dead before gemm writes g

    const int nbC = (E + CHUNK - 1) / CHUNK;
    const int nbA = (N + 31) / 32;        // aggregate: 32 nodes/block
    const int nbG = (N + 191) / 192;      // gemm: 192 rows/block

    zero_small<<<1, 256, 0, stream>>>(bhist, bcur);
    coarse_hist<<<nbC, 256, 0, stream>>>(dst, bhist, E, NB);
    scan196<<<1, 256, 0, stream>>>(bhist, boffs, NB, E);
    bucket_bin<<<nbC, 256, 0, stream>>>(src, dst, boffs, bcur, pairs, E, NB);
    csr_sort<<<NB, 1024, MAXB * 4, stream>>>(pairs, boffs, csr, cnt, offs, dinv, N);

    // layer 1
    gemm_scale<128><<<nbG, 192, 0, stream>>>(x, W1, dinv, g, N);
    aggregate<<<nbA, 256, 0, stream>>>(g, offs, cnt, csr, dinv, b1, a1, N, 1);
    // layer 2
    gemm_scale<64><<<nbG, 192, 0, stream>>>(a1, W2, dinv, g, N);
    aggregate<<<nbA, 256, 0, stream>>>(g, offs, cnt, csr, dinv, b2, out, N, 0);
}

// Round 7
// 400.296 us; speedup vs baseline: 1.0095x; 1.0095x over previous
//
#include <hip/hip_runtime.h>
#include <math.h>

// ---------------------------------------------------------------------------
// 2-layer GCN:  out = GCNConv(relu(GCNConv(x, W1, b1)), W2, b2)
// Factorization: g = (x@W) * dinv[row];  agg[d] = g[d] + sum_{s in in(d)} g[s];
//                out[d] = agg[d]*dinv[d] + b   (dinv = rsqrt(indeg+1))
//
// R1: per-node scatter -> 197MB partial-line writebacks. Fixed (bucket sort).
// R2: per-node histogram atomics -> 99.8MB writebacks. Fixed (LDS sort).
// R3->R5: bf16 G rows + wide gathers: aggregate 119 -> 61us.
// R6 lesson: 57.5KB-LDS gemm tile -> 2 blocks/CU, 6 waves, occupancy 5.9%,
//   latency-bound at 102us. R7 gemm: wave = 16-col group so W[k][cols] is
//   wave-uniform (scalar s_load, SGPR operand in v_fma); lane = row; LDS only
//   stages a 64x32 X chunk transposed at pitch 65 (8.3KB, conflict-free).
//   ~28 VGPR, ~8 waves/SIMD. 4 ds_read_b32 per 64 FMAs -> VALU-bound.
// ---------------------------------------------------------------------------

#define BKT_SHIFT 9               // 512 nodes per bucket
#define BKT_NODES 512
#define NBSH      256             // >= bucket count (196)
#define CHUNK     8192            // edges per bucket_bin/coarse_hist block
#define MAXB      20480           // max edges/bucket for LDS sort (mean ~16.3k)

typedef unsigned short ushort_t;

static __device__ __forceinline__ unsigned short f2bf(float f) {
    unsigned u = __float_as_uint(f);
    unsigned r = (u + 0x7FFFu + ((u >> 16) & 1u)) >> 16;   // RNE
    return (unsigned short)r;
}
static __device__ __forceinline__ float bf_lo(unsigned u) {
    return __uint_as_float(u << 16);
}
static __device__ __forceinline__ float bf_hi(unsigned u) {
    return __uint_as_float(u & 0xFFFF0000u);
}
static __device__ __forceinline__ void acc_add(float2* a, uint4 v) {
    a[0].x += bf_lo(v.x); a[0].y += bf_hi(v.x);
    a[1].x += bf_lo(v.y); a[1].y += bf_hi(v.y);
    a[2].x += bf_lo(v.z); a[2].y += bf_hi(v.z);
    a[3].x += bf_lo(v.w); a[3].y += bf_hi(v.w);
}

__global__ __launch_bounds__(256) void zero_small(int* __restrict__ bhist,
                                                  int* __restrict__ bcur) {
    int t = threadIdx.x;
    bhist[t] = 0;
    bcur[t]  = 0;
}

__global__ __launch_bounds__(256) void coarse_hist(const int* __restrict__ dst,
                                                   int* __restrict__ bhist,
                                                   int E, int NB) {
    __shared__ int h[NBSH];
    const int t  = threadIdx.x;
    const int e0 = blockIdx.x * CHUNK;
    const int n  = min(CHUNK, E - e0);
    h[t] = 0;
    __syncthreads();
    for (int i = t; i < n; i += 256) atomicAdd(&h[dst[e0 + i] >> BKT_SHIFT], 1);
    __syncthreads();
    if (t < NB && h[t] > 0) atomicAdd(&bhist[t], h[t]);
}

__global__ __launch_bounds__(256) void scan196(const int* __restrict__ bhist,
                                               int* __restrict__ boffs, int NB, int E) {
    __shared__ int sh[256];
    int t = threadIdx.x;
    int orig = (t < NB) ? bhist[t] : 0;
    sh[t] = orig;
    __syncthreads();
    for (int d = 1; d < 256; d <<= 1) {
        int u = (t >= d) ? sh[t - d] : 0;
        __syncthreads();
        sh[t] += u;
        __syncthreads();
    }
    if (t < NB) boffs[t] = sh[t] - orig;  // exclusive
    if (t == NB) boffs[NB] = E;
    if (t == 255 && NB < 255) boffs[NB] = E;
}

// Phase A: bin edges into buckets. Packed pair: (dst&511)<<17 | src  (src<2^17).
__global__ __launch_bounds__(256) void bucket_bin(const int* __restrict__ src,
                                                  const int* __restrict__ dst,
                                                  const int* __restrict__ boffs,
                                                  int* __restrict__ bcur,
                                                  unsigned* __restrict__ pairs,
                                                  int E, int NB) {
    __shared__ unsigned stag[CHUNK];   // 32KB
    __shared__ int hist[NBSH];
    __shared__ int lofs[NBSH];
    __shared__ int lcur[NBSH];
    __shared__ int gbase[NBSH];
    const int t  = threadIdx.x;
    const int e0 = blockIdx.x * CHUNK;
    const int n  = min(CHUNK, E - e0);

    for (int i = t; i < NBSH; i += 256) hist[i] = 0;
    __syncthreads();
    for (int i = t; i < n; i += 256) atomicAdd(&hist[dst[e0 + i] >> BKT_SHIFT], 1);
    __syncthreads();
    int v = hist[t];
    lofs[t] = v;
    __syncthreads();
    for (int d = 1; d < 256; d <<= 1) {
        int u = (t >= d) ? lofs[t - d] : 0;
        __syncthreads();
        lofs[t] += u;
        __syncthreads();
    }
    if (t < NB) {
        lcur[t]  = lofs[t] - v;
        gbase[t] = (v > 0) ? boffs[t] + atomicAdd(&bcur[t], v) : 0;
    }
    __syncthreads();
    for (int i = t; i < n; i += 256) {
        int d = dst[e0 + i];
        int s = src[e0 + i];
        int b = d >> BKT_SHIFT;
        int p = atomicAdd(&lcur[b], 1);
        stag[p] = ((unsigned)(d & (BKT_NODES - 1)) << 17) | (unsigned)s;
    }
    __syncthreads();
    const int wv = t >> 6, ln = t & 63;
    for (int b = wv; b < NB; b += 4) {
        int cb = hist[b];
        if (cb == 0) continue;
        int lo = lofs[b] - cb;
        int gb = gbase[b];
        for (int i = ln; i < cb; i += 64) pairs[gb + i] = stag[lo + i];
    }
}

// Phase B: per-bucket fine counting sort in LDS; emits cnt/offs/dinv coalesced.
__global__ __launch_bounds__(1024) void csr_sort(const unsigned* __restrict__ pairs,
                                                 const int* __restrict__ boffs,
                                                 int* __restrict__ csr,
                                                 int* __restrict__ cnt,
                                                 int* __restrict__ offs,
                                                 float* __restrict__ dinv,
                                                 int N) {
    extern __shared__ unsigned stag2[];   // MAXB entries (80KB)
    __shared__ int lhist[BKT_NODES];
    __shared__ int lofs[BKT_NODES];
    __shared__ int ncur[BKT_NODES];
    const int b    = blockIdx.x;
    const int t    = threadIdx.x;
    const int n0   = b << BKT_SHIFT;
    const int base = boffs[b];
    const int ne   = boffs[b + 1] - base;

    if (t < BKT_NODES) lhist[t] = 0;
    __syncthreads();
    for (int i = t; i < ne; i += 1024) atomicAdd(&lhist[pairs[base + i] >> 17], 1);
    __syncthreads();
    if (t < BKT_NODES) lofs[t] = lhist[t];
    __syncthreads();
    for (int d = 1; d < BKT_NODES; d <<= 1) {
        int u = (t < BKT_NODES && t >= d) ? lofs[t - d] : 0;
        __syncthreads();
        if (t < BKT_NODES) lofs[t] += u;
        __syncthreads();
    }
    if (t < BKT_NODES) {
        int node = n0 + t;
        int ex   = lofs[t] - lhist[t];
        ncur[t]  = ex;
        if (node < N) {
            cnt[node]  = lhist[t];
            offs[node] = base + ex;
            dinv[node] = rsqrtf((float)(lhist[t] + 1));
        }
    }
    __syncthreads();
    if (ne <= MAXB) {
        for (int i = t; i < ne; i += 1024) {
            unsigned p = pairs[base + i];
            int pos = atomicAdd(&ncur[p >> 17], 1);
            stag2[pos] = p & 0x1FFFFu;
        }
        __syncthreads();
        for (int i = t; i < ne; i += 1024) csr[base + i] = (int)stag2[i];
    } else {  // safety fallback
        for (int i = t; i < ne; i += 1024) {
            unsigned p = pairs[base + i];
            int pos = atomicAdd(&ncur[p >> 17], 1);
            csr[base + pos] = (int)(p & 0x1FFFFu);
        }
    }
}

// G[row] = bf16( (X[row] @ W) * dinv[row] ).  64 rows/block, 256 threads.
// lane = row; wave = 16-col group (cg wave-uniform via readfirstlane ->
// W loads are scalar s_load, used as the SGPR operand of v_fma).
// Xs: transposed [k][row] pitch 65 -> conflict-free b32 LDS reads/writes.
template <int K>
__global__ __launch_bounds__(256) void gemm_scale(const float* __restrict__ X,
                                                  const float* __restrict__ W,
                                                  const float* __restrict__ dinv,
                                                  ushort_t* __restrict__ G, int N) {
    __shared__ float Xs[32 * 65];
    const int t    = threadIdx.x;
    const int lane = t & 63;
    const int cg   = __builtin_amdgcn_readfirstlane((t >> 6) * 16);
    const int r0   = blockIdx.x * 64;
    const int r    = r0 + lane;

    float acc[16];
#pragma unroll
    for (int j = 0; j < 16; ++j) acc[j] = 0.f;

    for (int kc = 0; kc < K; kc += 32) {
        __syncthreads();
#pragma unroll
        for (int j = 0; j < 8; ++j) {
            int idx = t + j * 256;
            int kl  = idx & 31;       // lanes consecutive in k -> coalesced
            int row = idx >> 5;
            int gr  = r0 + row;
            float v = (gr < N) ? X[(size_t)gr * K + kc + kl] : 0.f;
            Xs[kl * 65 + row] = v;
        }
        __syncthreads();
#pragma unroll
        for (int k4 = 0; k4 < 8; ++k4) {
            float x0 = Xs[(k4 * 4 + 0) * 65 + lane];
            float x1 = Xs[(k4 * 4 + 1) * 65 + lane];
            float x2 = Xs[(k4 * 4 + 2) * 65 + lane];
            float x3 = Xs[(k4 * 4 + 3) * 65 + lane];
            const float* w0 = W + (size_t)(kc + k4 * 4) * 64 + cg;  // uniform
#pragma unroll
            for (int j = 0; j < 16; ++j) {
                float a = acc[j];
                a = fmaf(x0, w0[j], a);
                a = fmaf(x1, w0[64 + j], a);
                a = fmaf(x2, w0[128 + j], a);
                a = fmaf(x3, w0[192 + j], a);
                acc[j] = a;
            }
        }
    }

    if (r < N) {
        float s = dinv[r];
        uint4 u0, u1;
        u0.x = (unsigned)f2bf(acc[0] * s)  | ((unsigned)f2bf(acc[1] * s)  << 16);
        u0.y = (unsigned)f2bf(acc[2] * s)  | ((unsigned)f2bf(acc[3] * s)  << 16);
        u0.z = (unsigned)f2bf(acc[4] * s)  | ((unsigned)f2bf(acc[5] * s)  << 16);
        u0.w = (unsigned)f2bf(acc[6] * s)  | ((unsigned)f2bf(acc[7] * s)  << 16);
        u1.x = (unsigned)f2bf(acc[8] * s)  | ((unsigned)f2bf(acc[9] * s)  << 16);
        u1.y = (unsigned)f2bf(acc[10] * s) | ((unsigned)f2bf(acc[11] * s) << 16);
        u1.z = (unsigned)f2bf(acc[12] * s) | ((unsigned)f2bf(acc[13] * s) << 16);
        u1.w = (unsigned)f2bf(acc[14] * s) | ((unsigned)f2bf(acc[15] * s) << 16);
        *(uint4*)(G + (size_t)r * 64 + cg)     = u0;
        *(uint4*)(G + (size_t)r * 64 + cg + 8) = u1;
    }
}

// 8 nodes per wave: grp=lane>>3 picks the node, sub=lane&7 its 16B row chunk.
__global__ __launch_bounds__(256) void aggregate(const ushort_t* __restrict__ G,
                                                 const int* __restrict__ offs,
                                                 const int* __restrict__ cnt,
                                                 const int* __restrict__ csr,
                                                 const float* __restrict__ dinv,
                                                 const float* __restrict__ bias,
                                                 float* __restrict__ out, int N,
                                                 int do_relu) {
    int wid  = (blockIdx.x * 256 + threadIdx.x) >> 6;
    int lane = threadIdx.x & 63;
    int grp  = lane >> 3;
    int sub  = lane & 7;
    int node = wid * 8 + grp;
    if (node >= N) return;
    const int beg = offs[node];
    const int num = cnt[node];
    const size_t subo = (size_t)sub * 8;

    float2 acc[4];
    {   // self-loop
        uint4 v = *(const uint4*)(G + (size_t)node * 64 + subo);
        acc[0] = make_float2(bf_lo(v.x), bf_hi(v.x));
        acc[1] = make_float2(bf_lo(v.y), bf_hi(v.y));
        acc[2] = make_float2(bf_lo(v.z), bf_hi(v.z));
        acc[3] = make_float2(bf_lo(v.w), bf_hi(v.w));
    }
    int e = 0;
    for (; e + 2 <= num; e += 2) {
        int i0 = csr[beg + e];
        int i1 = csr[beg + e + 1];
        uint4 v0 = *(const uint4*)(G + (size_t)i0 * 64 + subo);
        uint4 v1 = *(const uint4*)(G + (size_t)i1 * 64 + subo);
        acc_add(acc, v0);
        acc_add(acc, v1);
    }
    if (e < num) {
        int i0 = csr[beg + e];
        uint4 v0 = *(const uint4*)(G + (size_t)i0 * 64 + subo);
        acc_add(acc, v0);
    }

    float dv  = dinv[node];
    float4 b0 = *(const float4*)(bias + sub * 8);
    float4 b1 = *(const float4*)(bias + sub * 8 + 4);
    float4 o0 = make_float4(fmaf(acc[0].x, dv, b0.x), fmaf(acc[0].y, dv, b0.y),
                            fmaf(acc[1].x, dv, b0.z), fmaf(acc[1].y, dv, b0.w));
    float4 o1 = make_float4(fmaf(acc[2].x, dv, b1.x), fmaf(acc[2].y, dv, b1.y),
                            fmaf(acc[3].x, dv, b1.z), fmaf(acc[3].y, dv, b1.w));
    if (do_relu) {
        o0.x = fmaxf(o0.x, 0.f); o0.y = fmaxf(o0.y, 0.f);
        o0.z = fmaxf(o0.z, 0.f); o0.w = fmaxf(o0.w, 0.f);
        o1.x = fmaxf(o1.x, 0.f); o1.y = fmaxf(o1.y, 0.f);
        o1.z = fmaxf(o1.z, 0.f); o1.w = fmaxf(o1.w, 0.f);
    }
    *(float4*)(out + (size_t)node * 64 + sub * 8)     = o0;
    *(float4*)(out + (size_t)node * 64 + sub * 8 + 4) = o1;
}

extern "C" void kernel_launch(void* const* d_in, const int* in_sizes, int n_in,
                              void* d_out, int out_size, void* d_ws, size_t ws_size,
                              hipStream_t stream) {
    const float* x  = (const float*)d_in[0];
    const int*   ei = (const int*)d_in[1];
    const float* W1 = (const float*)d_in[2];
    const float* b1 = (const float*)d_in[3];
    const float* W2 = (const float*)d_in[4];
    const float* b2 = (const float*)d_in[5];
    float* out = (float*)d_out;

    const int IN_CH = 128;
    const int N = in_sizes[0] / IN_CH;   // 100000
    const int E = in_sizes[1] / 2;       // 3200000
    const int* src = ei;
    const int* dst = ei + E;
    const int NB = (N + BKT_NODES - 1) >> BKT_SHIFT;  // 196

    char* ws = (char*)d_ws;
    size_t off = 0;
    auto take = [&](size_t bytes) -> char* {
        char* p = ws + off;
        off += (bytes + 255) & ~(size_t)255;
        return p;
    };
    int*      cnt   = (int*)take((size_t)N * 4);
    int*      offs  = (int*)take((size_t)N * 4);
    float*    dinv  = (float*)take((size_t)N * 4);
    int*      bhist = (int*)take(NBSH * 4);
    int*      boffs = (int*)take((NBSH + 1) * 4);
    int*      bcur  = (int*)take(NBSH * 4);
    int*      csr   = (int*)take((size_t)E * 4);
    ushort_t* g     = (ushort_t*)take((size_t)E * 4);       // >= N*64*2; aliases pairs
    float*    a1    = (float*)take((size_t)N * 64 * 4);
    unsigned* pairs = (unsigned*)g;  // pairs dead before gemm writes g

    const int nbC = (E + CHUNK - 1) / CHUNK;
    const int nbA = (N + 31) / 32;        // aggregate: 32 nodes/block
    const int nbG = (N + 63) / 64;        // gemm: 64 rows/block

    zero_small<<<1, 256, 0, stream>>>(bhist, bcur);
    coarse_hist<<<nbC, 256, 0, stream>>>(dst, bhist, E, NB);
    scan196<<<1, 256, 0, stream>>>(bhist, boffs, NB, E);
    bucket_bin<<<nbC, 256, 0, stream>>>(src, dst, boffs, bcur, pairs, E, NB);
    csr_sort<<<NB, 1024, MAXB * 4, stream>>>(pairs, boffs, csr, cnt, offs, dinv, N);

    // layer 1
    gemm_scale<128><<<nbG, 256, 0, stream>>>(x, W1, dinv, g, N);
    aggregate<<<nbA, 256, 0, stream>>>(g, offs, cnt, csr, dinv, b1, a1, N, 1);
    // layer 2
    gemm_scale<64><<<nbG, 256, 0, stream>>>(a1, W2, dinv, g, N);
    aggregate<<<nbA, 256, 0, stream>>>(g, offs, cnt, csr, dinv, b2, out, N, 0);
}